// Round 7
// baseline (277.283 us; speedup 1.0000x reference)
//
#include <hip/hip_runtime.h>

// Problem constants (B,S,D_IN,D_HID,D_OUT) = (8,4096,512,1024,512)
#define B_    8
#define S_    4096
#define DIN   512
#define DHID  1024
#define DOUT  512
#define M_    (B_*S_)          // 32768
#define NCAT  (DHID + DOUT)    // 1536
#define CH2   32
#define NCH2  (S_/CH2)         // 128

typedef __bf16 bf16x8 __attribute__((ext_vector_type(8)));
typedef float  floatx4 __attribute__((ext_vector_type(4)));

__device__ __forceinline__ unsigned short f2bf(float f) {
  unsigned u = __builtin_bit_cast(unsigned, f);
  u = (u + 0x7FFFu + ((u >> 16) & 1u)) >> 16;   // RNE
  return (unsigned short)u;
}
__device__ __forceinline__ float bf2f(unsigned short h) {
  unsigned u = ((unsigned)h) << 16;
  return __builtin_bit_cast(float, u);
}

__device__ __forceinline__ void gl_lds16(const unsigned short* g, unsigned short* l) {
  __builtin_amdgcn_global_load_lds((const __attribute__((address_space(1))) void*)g,
                                   (__attribute__((address_space(3))) void*)l, 16, 0, 0);
}

// ---------- fused prep: wcat | woutt | a_s | x->bf16 (single launch) ----------
__global__ void prep_all(const float* __restrict__ logit,
                         const float* __restrict__ Win, const float* __restrict__ Wdx,
                         const float* __restrict__ Wout, const float* __restrict__ x,
                         float* __restrict__ a_s,
                         unsigned short* __restrict__ wcat,
                         unsigned short* __restrict__ woutt,
                         unsigned short* __restrict__ xb) {
  int bx = blockIdx.x;
  if (bx < 3072) {                       // Wcat^T: n in [0,1536), k in [0,512)
    int idx = bx * 256 + threadIdx.x;
    int n = idx >> 9, k = idx & 511;
    float v = (n < DHID) ? Win[(size_t)k * DHID + n] : Wdx[(size_t)k * DOUT + (n - DHID)];
    wcat[idx] = f2bf(v);
  } else if (bx < 5120) {                // Wout^T: n in [0,512), k in [0,1024)
    int idx = (bx - 3072) * 256 + threadIdx.x;
    int n = idx >> 10, k = idx & 1023;
    woutt[idx] = f2bf(Wout[(size_t)k * DOUT + n]);
  } else if (bx < 5124) {                // a_s
    int d = (bx - 5120) * 256 + threadIdx.x;
    if (d < DHID) {
      float a = 1.f / (1.f + expf(-logit[d]));
      a_s[d] = a;
      a_s[DHID + d] = sqrtf(fmaxf(1.f - a * a, 0.f));
    }
  } else {                               // x fp32 -> bf16, 8 elems/thread
    size_t i = (size_t)(bx - 5124) * 256 + threadIdx.x;
    const float4* p = (const float4*)x;
    float4 v0 = p[i * 2];
    float4 v1 = p[i * 2 + 1];
    uint4 o;
    o.x = (unsigned)f2bf(v0.x) | ((unsigned)f2bf(v0.y) << 16);
    o.y = (unsigned)f2bf(v0.z) | ((unsigned)f2bf(v0.w) << 16);
    o.z = (unsigned)f2bf(v1.x) | ((unsigned)f2bf(v1.y) << 16);
    o.w = (unsigned)f2bf(v1.z) | ((unsigned)f2bf(v1.w) << 16);
    *(uint4*)&xb[i * 8] = o;
  }
}

// ============ 256x128 GEMM, 8 waves x 64x64, 3-slot BK=32, 2 blocks/CU ============
// Occupancy play: acc 64 AGPR + ~60 VGPR (<=128 unified -> 4 waves/SIMD) and
// LDS 3 x 24 KB = 72 KB (2 x 72 <= 160) -> TWO blocks/CU so barrier/vmcnt stalls
// overlap across blocks. Same proven swizzle: LDS linear for global_load_lds,
// source chunk pre-XOR'd, ds_read chunk ^= ((row>>1)&3). Counted vmcnt: distance-2,
// vmcnt(3) steady state, drains only in tail. Epilogue conflict-free (stride 132).
// MODE 0: C = xb @ Wcat^T; n0<1024: u=(c+b_in)*s bf16 + fused chunk-scan -> carry;
//         else dx=c+b_dx bf16.   MODE 1: out = (c + b_out + dx)*0.5 fp32.
template <int K, int MODE, int NTN>
__global__ __launch_bounds__(512, 4) void gemm128n(
    const unsigned short* __restrict__ A,
    const unsigned short* __restrict__ Bt,
    const float* __restrict__ a_s,
    const float* __restrict__ bias0,
    const float* __restrict__ bias1,
    unsigned short* __restrict__ u_out,
    unsigned short* __restrict__ dx_buf,
    const unsigned short* __restrict__ dx_in,
    float* __restrict__ out,
    float* __restrict__ carry)
{
  constexpr int NG = K / 32;             // granules
  __shared__ __align__(16) unsigned char smem[73728];   // 3 slots x 24 KB
  unsigned char* lds = smem;

  const int tid  = threadIdx.x;
  const int lane = tid & 63, wid = tid >> 6;
  const int r16  = lane & 15, quad = lane >> 4;
  const int wm = (wid >> 1) * 64, wn = (wid & 1) * 64;   // 4M x 2N wave grid
  const int csw = (quad ^ ((r16 >> 1) & 3)) << 4;        // read-side swizzled 16B chunk

  // XCD-aware bijective block swizzle
  constexpr int TOT = (M_ / 256) * NTN;
  const int flat = blockIdx.x;
  const int jj = (flat & 7) * (TOT / 8) + (flat >> 3);
  const int nt = jj % NTN, mt = jj / NTN;
  const int n0 = nt * 128, m0 = mt * 256;

  // staging: A 256x32 (2 loads/thr) + B 128x32 (1 load/thr); src pre-swizzled
  const int srow = tid >> 2;                              // 0..127
  const int scol = ((tid & 3) ^ ((tid >> 3) & 3)) << 3;   // pre-swizzled src chunk
  const unsigned short* gA0 = A  + (size_t)(m0 + srow) * K + scol;
  const unsigned short* gA1 = gA0 + (size_t)128 * K;
  const unsigned short* gB0 = Bt + (size_t)(n0 + srow) * K + scol;
  const unsigned o16 = (unsigned)tid * 16u;               // linear LDS bytes

  floatx4 acc[4][4] = {};

  auto stage = [&](int slot, int g) {
    unsigned char* d = lds + slot * 24576;
    gl_lds16(gA0 + (size_t)g * 32, (unsigned short*)(d + o16));
    gl_lds16(gA1 + (size_t)g * 32, (unsigned short*)(d + 8192 + o16));
    gl_lds16(gB0 + (size_t)g * 32, (unsigned short*)(d + 16384 + o16));
  };

  auto compute = [&](int slot) {
    const unsigned char* pA = lds + slot * 24576;
    const unsigned char* pB = pA + 16384;
    bf16x8 af[4], bfr[4];
#pragma unroll
    for (int j = 0; j < 4; ++j)
      bfr[j] = *(const bf16x8*)(pB + (wn + j * 16 + r16) * 64 + csw);
#pragma unroll
    for (int i = 0; i < 4; ++i)
      af[i] = *(const bf16x8*)(pA + (wm + i * 16 + r16) * 64 + csw);
    __builtin_amdgcn_s_setprio(1);
#pragma unroll
    for (int i = 0; i < 4; ++i)
#pragma unroll
      for (int j = 0; j < 4; ++j)
        acc[i][j] = __builtin_amdgcn_mfma_f32_16x16x32_bf16(af[i], bfr[j], acc[i][j], 0, 0, 0);
    __builtin_amdgcn_s_setprio(0);
  };

  // prologue: granules 0,1 in flight (6 loads); wait g0 landed (3 newer allowed)
  stage(0, 0); stage(1, 1);
  asm volatile("s_waitcnt vmcnt(3)" ::: "memory");
  __builtin_amdgcn_s_barrier();

  // steady: stage g+2 (slot of g-1, freed), compute g, wait g+1 landed
  for (int t = 0; t < NG - 2; ++t) {
    stage((t + 2) % 3, t + 2);
    compute(t % 3);
    asm volatile("s_waitcnt vmcnt(3) lgkmcnt(0)" ::: "memory");
    __builtin_amdgcn_s_barrier();
  }
  compute((NG - 2) % 3);
  asm volatile("s_waitcnt vmcnt(0) lgkmcnt(0)" ::: "memory");
  __builtin_amdgcn_s_barrier();
  compute((NG - 1) % 3);
  asm volatile("s_waitcnt lgkmcnt(0)" ::: "memory");
  __builtin_amdgcn_s_barrier();

  // ---- epilogue (conflict-free): 4 passes of 64 rows, fp32 stride 132 ----
  float* stg = (float*)smem;                             // 64 x 132 = 33.8 KB
  const bool isU = (MODE == 0) && (n0 < DHID);
  const int sg = tid & 15, rw = tid >> 4;                // store: col-group, row

  float4 bv0 = {}, bv1 = {}, sv0 = {}, sv1 = {};
  if (MODE == 0) {
    if (isU) {
      bv0 = *(const float4*)&bias0[n0 + sg * 8];
      bv1 = *(const float4*)&bias0[n0 + sg * 8 + 4];
      sv0 = *(const float4*)&a_s[DHID + n0 + sg * 8];
      sv1 = *(const float4*)&a_s[DHID + n0 + sg * 8 + 4];
    } else {
      bv0 = *(const float4*)&bias1[(n0 - DHID) + sg * 8];
      bv1 = *(const float4*)&bias1[(n0 - DHID) + sg * 8 + 4];
    }
  } else {
    bv0 = *(const float4*)&bias0[n0 + sg * 8];
    bv1 = *(const float4*)&bias0[n0 + sg * 8 + 4];
  }

  // fused-scan mapping: tid<256 -> 128 cols x 2 chunks of 32 rows per pass
  const int colS = tid & 127, chk = (tid >> 7) & 1;
  float aa = 0.f, sbi = 0.f, ssc = 0.f;
  if (isU && tid < 256) {
    aa = a_s[n0 + colS]; sbi = bias0[n0 + colS]; ssc = a_s[DHID + n0 + colS];
  }

#pragma unroll
  for (int p = 0; p < 4; ++p) {
    if ((wid >> 1) == p) {              // the 2 waves owning this 64-row band
#pragma unroll
      for (int i = 0; i < 4; ++i)
#pragma unroll
        for (int j = 0; j < 4; ++j) {
          const int col = wn + j * 16 + r16;
#pragma unroll
          for (int r = 0; r < 4; ++r)
            stg[(i * 16 + quad * 4 + r) * 132 + col] = acc[i][j][r];
        }
    }
    asm volatile("s_waitcnt lgkmcnt(0)" ::: "memory");
    __builtin_amdgcn_s_barrier();

    const int gmb = m0 + p * 64;
    if (isU) {
      if (tid < 256) {                  // chunk-local weighted scan (2 full chunks)
        float P = 0.f;
        const float* sp = &stg[(chk * 32) * 132 + colS];
#pragma unroll
        for (int r = 0; r < 32; ++r) { P = fmaf(aa, P, (sp[0] + sbi) * ssc); sp += 132; }
        const int gm0 = gmb + chk * 32;
        carry[((size_t)(gm0 >> 12) * NCH2 + ((gm0 & 4095) >> 5)) * DHID + n0 + colS] = P;
      }
#pragma unroll
      for (int q = 0; q < 2; ++q) {
        const int lr = rw + q * 32;
        float4 v0 = *(const float4*)&stg[lr * 132 + sg * 8];
        float4 v1 = *(const float4*)&stg[lr * 132 + sg * 8 + 4];
        union { unsigned short s[8]; uint4 u4; } ub;
        ub.s[0] = f2bf((v0.x + bv0.x) * sv0.x);
        ub.s[1] = f2bf((v0.y + bv0.y) * sv0.y);
        ub.s[2] = f2bf((v0.z + bv0.z) * sv0.z);
        ub.s[3] = f2bf((v0.w + bv0.w) * sv0.w);
        ub.s[4] = f2bf((v1.x + bv1.x) * sv1.x);
        ub.s[5] = f2bf((v1.y + bv1.y) * sv1.y);
        ub.s[6] = f2bf((v1.z + bv1.z) * sv1.z);
        ub.s[7] = f2bf((v1.w + bv1.w) * sv1.w);
        *(uint4*)&u_out[(size_t)(gmb + lr) * DHID + n0 + sg * 8] = ub.u4;
      }
    } else if (MODE == 0) {
#pragma unroll
      for (int q = 0; q < 2; ++q) {
        const int lr = rw + q * 32;
        float4 v0 = *(const float4*)&stg[lr * 132 + sg * 8];
        float4 v1 = *(const float4*)&stg[lr * 132 + sg * 8 + 4];
        union { unsigned short s[8]; uint4 u4; } ub;
        ub.s[0] = f2bf(v0.x + bv0.x);
        ub.s[1] = f2bf(v0.y + bv0.y);
        ub.s[2] = f2bf(v0.z + bv0.z);
        ub.s[3] = f2bf(v0.w + bv0.w);
        ub.s[4] = f2bf(v1.x + bv1.x);
        ub.s[5] = f2bf(v1.y + bv1.y);
        ub.s[6] = f2bf(v1.z + bv1.z);
        ub.s[7] = f2bf(v1.w + bv1.w);
        *(uint4*)&dx_buf[(size_t)(gmb + lr) * DOUT + (n0 - DHID) + sg * 8] = ub.u4;
      }
    } else {
#pragma unroll
      for (int q = 0; q < 2; ++q) {
        const int lr = rw + q * 32;
        float4 v0 = *(const float4*)&stg[lr * 132 + sg * 8];
        float4 v1 = *(const float4*)&stg[lr * 132 + sg * 8 + 4];
        ushort4 d0 = *(const ushort4*)&dx_in[(size_t)(gmb + lr) * DOUT + n0 + sg * 8];
        ushort4 d1 = *(const ushort4*)&dx_in[(size_t)(gmb + lr) * DOUT + n0 + sg * 8 + 4];
        float4 o0, o1;
        o0.x = (v0.x + bv0.x + bf2f(d0.x)) * 0.5f;
        o0.y = (v0.y + bv0.y + bf2f(d0.y)) * 0.5f;
        o0.z = (v0.z + bv0.z + bf2f(d0.z)) * 0.5f;
        o0.w = (v0.w + bv0.w + bf2f(d0.w)) * 0.5f;
        o1.x = (v1.x + bv1.x + bf2f(d1.x)) * 0.5f;
        o1.y = (v1.y + bv1.y + bf2f(d1.y)) * 0.5f;
        o1.z = (v1.z + bv1.z + bf2f(d1.z)) * 0.5f;
        o1.w = (v1.w + bv1.w + bf2f(d1.w)) * 0.5f;
        *(float4*)&out[(size_t)(gmb + lr) * DOUT + n0 + sg * 8]     = o0;
        *(float4*)&out[(size_t)(gmb + lr) * DOUT + n0 + sg * 8 + 4] = o1;
      }
    }
    __builtin_amdgcn_s_barrier();
  }
}

// ---------- scan kernels ----------
__global__ __launch_bounds__(256) void scan_mid(const float* __restrict__ a_s,
                                                const float* __restrict__ h0,
                                                float* __restrict__ carry,
                                                float* __restrict__ h_last) {
  int idx = blockIdx.x * 256 + threadIdx.x;   // B_*DHID = 8192
  int d = idx & (DHID - 1);
  int b = idx >> 10;
  float a = a_s[d];
  float aL = a;
#pragma unroll
  for (int q = 0; q < 5; ++q) aL *= aL;       // a^32
  float st = h0[(size_t)b * DHID + d];
  float* p = &carry[(size_t)b * NCH2 * DHID + d];
  for (int cg = 0; cg < NCH2; cg += 8) {
    float loc[8];
#pragma unroll
    for (int j = 0; j < 8; ++j) loc[j] = p[(size_t)j * DHID];
#pragma unroll
    for (int j = 0; j < 8; ++j) {
      p[(size_t)j * DHID] = st;
      st = fmaf(aL, st, loc[j]);
    }
    p += (size_t)8 * DHID;
  }
  h_last[(size_t)b * DHID + d] = st;
}

// r3-proven d8 variant (d4 regressed ~5us in r6 — reverted)
__global__ __launch_bounds__(256) void scan2(unsigned short* __restrict__ u,
                                             const float* __restrict__ a_s,
                                             const float* __restrict__ carry) {
  int idx = blockIdx.x * 256 + threadIdx.x;
  int d8 = (idx & 127) * 8;
  int c  = (idx >> 7) & (NCH2 - 1);
  int b  = idx >> 14;
  float4 a0 = *(const float4*)&a_s[d8];
  float4 a1 = *(const float4*)&a_s[d8 + 4];
  const float* cp = &carry[((size_t)(b * NCH2 + c)) * DHID + d8];
  float4 e0 = *(const float4*)cp;
  float4 e1 = *(const float4*)(cp + 4);
  float h0_ = e0.x, h1 = e0.y, h2 = e0.z, h3 = e0.w;
  float h4 = e1.x, h5 = e1.y, h6 = e1.z, h7 = e1.w;
  unsigned short* up = u + ((size_t)(b * S_ + c * CH2)) * DHID + d8;
#pragma unroll 4
  for (int t = 0; t < CH2; ++t) {
    ushort4 q0 = *(const ushort4*)up;
    ushort4 q1 = *(const ushort4*)(up + 4);
    h0_ = fmaf(a0.x, h0_, bf2f(q0.x)); h1 = fmaf(a0.y, h1, bf2f(q0.y));
    h2  = fmaf(a0.z, h2,  bf2f(q0.z)); h3 = fmaf(a0.w, h3, bf2f(q0.w));
    h4  = fmaf(a1.x, h4,  bf2f(q1.x)); h5 = fmaf(a1.y, h5, bf2f(q1.y));
    h6  = fmaf(a1.z, h6,  bf2f(q1.z)); h7 = fmaf(a1.w, h7, bf2f(q1.w));
    ushort4 w0, w1;
    w0.x = f2bf(h0_); w0.y = f2bf(h1); w0.z = f2bf(h2); w0.w = f2bf(h3);
    w1.x = f2bf(h4);  w1.y = f2bf(h5); w1.z = f2bf(h6); w1.w = f2bf(h7);
    *(ushort4*)up = w0;
    *(ushort4*)(up + 4) = w1;
    up += DHID;
  }
}

extern "C" void kernel_launch(void* const* d_in, const int* in_sizes, int n_in,
                              void* d_out, int out_size, void* d_ws, size_t ws_size,
                              hipStream_t stream) {
  const float* x    = (const float*)d_in[0];
  const float* h0   = (const float*)d_in[1];
  const float* alog = (const float*)d_in[2];
  const float* Wdx  = (const float*)d_in[3];
  const float* bdx  = (const float*)d_in[4];
  const float* Win  = (const float*)d_in[5];
  const float* bin  = (const float*)d_in[6];
  const float* Wout = (const float*)d_in[7];
  const float* bout = (const float*)d_in[8];

  float* out    = (float*)d_out;
  float* h_last = out + (size_t)M_ * DOUT;

  char* ws = (char*)d_ws;
  unsigned short* xb    = (unsigned short*)(ws);                      // 32 MB
  unsigned short* ubuf  = (unsigned short*)(ws + 33554432ull);        // 64 MB (u -> h in-place)
  unsigned short* dxb   = (unsigned short*)(ws + 100663296ull);       // 32 MB
  unsigned short* wcat  = (unsigned short*)(ws + 134217728ull);       // 1.5 MB
  unsigned short* woutt = (unsigned short*)(ws + 135790592ull);       // 1 MB
  float*          a_s   = (float*)(ws + 136839168ull);                // 8 KB
  float*          carry = (float*)(ws + 136847360ull);                // 4 MB

  // 1 launch: all weight transposes + gate precompute + x->bf16
  prep_all<<<5124 + (M_ * DIN / 8) / 256, 256, 0, stream>>>(
      alog, Win, Wdx, Wout, x, a_s, wcat, woutt, xb);

  // GEMM1 merged (+fused chunk-local scan): 256x128 tile, 2 blocks/CU
  gemm128n<DIN, 0, 12><<<dim3((M_ / 256) * 12), dim3(512), 0, stream>>>(
      xb, wcat, a_s, bin, bdx, ubuf, dxb, nullptr, nullptr, carry);

  // prefix over chunks + h_last
  scan_mid<<<(B_ * DHID) / 256, 256, 0, stream>>>(a_s, h0, carry, h_last);
  // full scan from exact entry states, u -> h in place
  scan2   <<<(B_ * NCH2 * (DHID / 8)) / 256, 256, 0, stream>>>(ubuf, a_s, carry);

  // GEMM2: out = (dx + h@W_out + b_out)/2
  gemm128n<DHID, 1, 4><<<dim3((M_ / 256) * 4), dim3(512), 0, stream>>>(
      ubuf, woutt, nullptr, bout, nullptr, nullptr, nullptr, dxb, out, nullptr);
}